// Round 1
// baseline (1181.485 us; speedup 1.0000x reference)
//
#include <hip/hip_runtime.h>
#include <math.h>

#define NNODES 100000
#define NEDGES 3200000
#define NFEAT  500
#define HID    64
#define NCLS   40
#define NLAYERS 8
#define NPB    16      // spmm nodes per block (quarter-wave gather: 4 nodes/wave)
#define NODES_PER_PART 12500   // NNODES / 8 (XCD-partitioned build)

typedef __attribute__((ext_vector_type(8))) short short8;   // 8 bf16 (4 VGPRs)
typedef __attribute__((ext_vector_type(4))) float floatx4;  // MFMA acc

static __device__ __forceinline__ float b2f(unsigned short u) {
    return __uint_as_float(((unsigned)u) << 16);
}
static __device__ __forceinline__ unsigned short f2b(float f) {
    unsigned u = __float_as_uint(f);
    return (unsigned short)((u + 0x7FFFu + ((u >> 16) & 1u)) >> 16);  // RNE
}
static __device__ __forceinline__ ushort4 pk4(float4 v) {
    return make_ushort4(f2b(v.x), f2b(v.y), f2b(v.z), f2b(v.w));
}

// ---------------- lin0: h0 = relu(x @ W + b)  --  MFMA bf16 GEMM ----------------
// block: 256 thr / 4 waves, tile M=128 x N=64, K chunks of 32 (500 padded to 512).
__global__ __launch_bounds__(256) void lin0_kernel(const float* __restrict__ x,
    const float* __restrict__ w, const float* __restrict__ b,
    unsigned short* __restrict__ h0)
{
    __shared__ unsigned short as_[128][40];  // A tile bf16 [m][k], rows padded 32->40
    __shared__ unsigned short wt[64][40];    // W^T chunk bf16 [n][k]
    const int tid = threadIdx.x;
    const int wv = tid >> 6, lane = tid & 63;
    const int ln15 = lane & 15, q = lane >> 4;
    const int m0 = blockIdx.x * 128;

    floatx4 acc[2][4];
#pragma unroll
    for (int i = 0; i < 2; ++i)
#pragma unroll
        for (int t = 0; t < 4; ++t) acc[i][t] = (floatx4){0.f, 0.f, 0.f, 0.f};

    const int r_ = tid >> 1, hh = tid & 1;       // staging: row, 16-float half
    int gms = m0 + r_; if (gms >= NNODES) gms = NNODES - 1;
    const float* xrow = x + (size_t)gms * NFEAT;

    for (int c = 0; c < 16; ++c) {
        const int k0 = c * 32;
        // ---- stage A: 128 x 32 fp32 -> bf16 ----
        {
            float4 v0, v1, v2, v3;
            if (c < 15 || hh == 0) {
                const float4* p4 = (const float4*)(xrow + k0 + 16 * hh);
                v0 = p4[0]; v1 = p4[1]; v2 = p4[2]; v3 = p4[3];
            } else {  // tail: k 496..511, only 496..499 valid
                v0 = *(const float4*)(xrow + 496);
                v1 = make_float4(0, 0, 0, 0); v2 = v1; v3 = v1;
            }
            ushort4* dst4 = (ushort4*)&as_[r_][16 * hh];
            dst4[0] = pk4(v0); dst4[1] = pk4(v1); dst4[2] = pk4(v2); dst4[3] = pk4(v3);
        }
        // ---- stage W^T: 32 x 64 fp32 -> bf16 [n][k] ----
#pragma unroll
        for (int ii = 0; ii < 2; ++ii) {
            int i = tid + ii * 256;               // float4 index in chunk (512 total)
            int k = i >> 4, nb = (i & 15) * 4;
            float4 v = make_float4(0, 0, 0, 0);
            if (c < 15 || i < 320)                // k0+k < 500
                v = ((const float4*)(w + (size_t)k0 * HID))[i];
            wt[nb + 0][k] = f2b(v.x); wt[nb + 1][k] = f2b(v.y);
            wt[nb + 2][k] = f2b(v.z); wt[nb + 3][k] = f2b(v.w);
        }
        __syncthreads();
        // ---- frags + MFMA ----
        short8 af[2], bfr[4];
#pragma unroll
        for (int mt = 0; mt < 2; ++mt)
            af[mt] = *(const short8*)&as_[32 * wv + 16 * mt + ln15][8 * q];
#pragma unroll
        for (int t = 0; t < 4; ++t)
            bfr[t] = *(const short8*)&wt[16 * t + ln15][8 * q];
#pragma unroll
        for (int mt = 0; mt < 2; ++mt)
#pragma unroll
            for (int t = 0; t < 4; ++t)
                acc[mt][t] = __builtin_amdgcn_mfma_f32_16x16x32_bf16(
                    af[mt], bfr[t], acc[mt][t], 0, 0, 0);
        __syncthreads();
    }
    // ---- epilogue: C/D layout col=lane&15, row=q*4+reg ----
    float bv[4];
#pragma unroll
    for (int t = 0; t < 4; ++t) bv[t] = b[16 * t + ln15];
#pragma unroll
    for (int mt = 0; mt < 2; ++mt)
#pragma unroll
        for (int r = 0; r < 4; ++r) {
            int gm = m0 + 32 * wv + 16 * mt + q * 4 + r;
            if (gm < NNODES) {
#pragma unroll
                for (int t = 0; t < 4; ++t)
                    h0[(size_t)gm * HID + 16 * t + ln15] =
                        f2b(fmaxf(acc[mt][t][r] + bv[t], 0.f));
            }
        }
}

// ---------------- CSR build (dst-sorted, deg padded to mult of 4) --------
// XCD-partitioned: block (slice=bid>>3, part=bid&7) handles only dst in its
// 12.5k-node range -> atomics/writes stay in one XCD's L2.
__global__ __launch_bounds__(256) void count_kernel(const int* __restrict__ dst,
                                                    int* __restrict__ deg)
{
    const int part = blockIdx.x & 7;
    const int e = (blockIdx.x >> 3) * 256 + threadIdx.x;
    const int d = dst[e];
    if (d / NODES_PER_PART == part) atomicAdd(&deg[d], 1);
}

__global__ __launch_bounds__(1024) void chunk_sum_kernel(const int* __restrict__ deg,
                                                         int* __restrict__ csum)
{
    __shared__ int s[1024];
    int i = blockIdx.x * 1024 + threadIdx.x;
    s[threadIdx.x] = (i < NNODES) ? ((deg[i] + 3) & ~3) : 0;
    __syncthreads();
    for (int off = 512; off > 0; off >>= 1) {
        if (threadIdx.x < off) s[threadIdx.x] += s[threadIdx.x + off];
        __syncthreads();
    }
    if (threadIdx.x == 0) csum[blockIdx.x] = s[0];
}

// one block, shared-mem scan over nchunks (<=128) -- replaces 1-thread serial loop
__global__ __launch_bounds__(128) void chunk_base_kernel(const int* __restrict__ csum,
    int* __restrict__ cbase, int* __restrict__ offs, int nchunks)
{
    __shared__ int s[128];
    const int t = threadIdx.x;
    int v = (t < nchunks) ? csum[t] : 0;
    s[t] = v;
    __syncthreads();
    for (int off = 1; off < 128; off <<= 1) {
        int u = (t >= off) ? s[t - off] : 0;
        __syncthreads();
        s[t] += u;
        __syncthreads();
    }
    if (t < nchunks) cbase[t] = s[t] - v;          // exclusive prefix
    if (t == nchunks - 1) offs[NNODES] = s[t];     // grand total
}

__global__ __launch_bounds__(1024) void scan_kernel(const int* __restrict__ deg,
    const int* __restrict__ cbase, int* __restrict__ offs, int* __restrict__ cursor)
{
    __shared__ int s[1024];
    int i = blockIdx.x * 1024 + threadIdx.x;
    int v = (i < NNODES) ? ((deg[i] + 3) & ~3) : 0;
    s[threadIdx.x] = v;
    __syncthreads();
    for (int off = 1; off < 1024; off <<= 1) {
        int t = (threadIdx.x >= off) ? s[threadIdx.x - off] : 0;
        __syncthreads();
        s[threadIdx.x] += t;
        __syncthreads();
    }
    if (i < NNODES) {
        int excl = cbase[blockIdx.x] + s[threadIdx.x] - v;
        offs[i] = excl;
        cursor[i] = excl;
    }
}

__global__ __launch_bounds__(256) void scatter_kernel(const int* __restrict__ src,
    const int* __restrict__ dst, const float* __restrict__ w,
    int* __restrict__ cursor, int2* __restrict__ srcw)
{
    const int part = blockIdx.x & 7;
    const int e = (blockIdx.x >> 3) * 256 + threadIdx.x;
    const int d = dst[e];
    if (d / NODES_PER_PART == part) {
        int pos = atomicAdd(&cursor[d], 1);
        srcw[pos] = make_int2(src[e] * 128, __float_as_int(w[e]));  // byte offset
    }
}

__global__ __launch_bounds__(256) void pad_kernel(const int* __restrict__ offs,
    const int* __restrict__ deg, int2* __restrict__ srcw)
{
    int n = blockIdx.x * 256 + threadIdx.x;
    if (n < NNODES) {
        int e = offs[n] + deg[n], e1 = offs[n + 1];
        for (; e < e1; ++e) srcw[e] = make_int2(0, 0);
    }
}

// ---------------- fused SpMM + blend + dense + relu layer ----------------
// Gather: QUARTER-wave per node (4 nodes/wave), uint2 (8B)/lane -> one row load
//   instr fetches four 128B rows; srcw read as int4 (2 edges per load, legal
//   since deg padded to x4 -> 16B aligned). Halves VMEM+VALU issue per edge.
// Dense: MFMA 16x16x32 bf16 -- z (16x64) @ W (64x64) in 8 MFMAs/block instead
//   of ~12K ds_read_b128/block on the VALU path (dense LDS traffic ~150x down).
__global__ __launch_bounds__(256) void spmm_layer_kernel(
    const unsigned short* __restrict__ h_in, const unsigned short* __restrict__ x0,
    unsigned short* __restrict__ h_out, const int* __restrict__ offs,
    const int2* __restrict__ srcw, const float* __restrict__ Wg, float beta)
{
    __shared__ float          zs [NPB][72];  // f32 z (residual term), 72-pad: 16B-aligned rows
    __shared__ unsigned short zsb[NPB][72];  // bf16 z (MFMA A operand)
    __shared__ unsigned short WbT[HID][72];  // bf16 W^T: WbT[j][k] = Wg[k][j]
    const int tid = threadIdx.x;

    // ---- stage WbT (fp32 -> bf16, transposed) ----
    for (int i = tid; i < 1024; i += 256) {
        float4 v = ((const float4*)Wg)[i];
        int k = i >> 4, j = (i & 15) * 4;
        WbT[j + 0][k] = f2b(v.x); WbT[j + 1][k] = f2b(v.y);
        WbT[j + 2][k] = f2b(v.z); WbT[j + 3][k] = f2b(v.w);
    }

    const int wv = tid >> 6, lane = tid & 63;
    const int qt = lane >> 4, ln = lane & 15;   // quarter id, lane-in-quarter
    const int nloc = wv * 4 + qt;               // local node 0..15
    const int n = blockIdx.x * NPB + nloc;
    int e = offs[n];
    const int e1 = offs[n + 1];
    const char* hbl = (const char*)h_in + ln * 8;
    float a0 = 0.f, a1 = 0.f, a2 = 0.f, a3 = 0.f;
#pragma unroll 2
    for (; e < e1; e += 2) {        // deg padded to multiple of 4
        int4 pr = *(const int4*)(srcw + e);          // 2 edges
        uint2 v0 = *(const uint2*)(hbl + pr.x);
        uint2 v1 = *(const uint2*)(hbl + pr.z);
        float w0 = __int_as_float(pr.y), w1 = __int_as_float(pr.w);
        a0 = fmaf(w0, __uint_as_float(v0.x << 16), a0);
        a1 = fmaf(w0, __uint_as_float(v0.x & 0xffff0000u), a1);
        a2 = fmaf(w0, __uint_as_float(v0.y << 16), a2);
        a3 = fmaf(w0, __uint_as_float(v0.y & 0xffff0000u), a3);
        a0 = fmaf(w1, __uint_as_float(v1.x << 16), a0);
        a1 = fmaf(w1, __uint_as_float(v1.x & 0xffff0000u), a1);
        a2 = fmaf(w1, __uint_as_float(v1.y << 16), a2);
        a3 = fmaf(w1, __uint_as_float(v1.y & 0xffff0000u), a3);
    }
    // blend with initial residual x0 (bf16), write f32 + bf16 copies of z
    uint2 xv = *(const uint2*)((const char*)x0 + (size_t)n * 128 + ln * 8);
    float z0 = 0.9f * a0 + 0.1f * __uint_as_float(xv.x << 16);
    float z1 = 0.9f * a1 + 0.1f * __uint_as_float(xv.x & 0xffff0000u);
    float z2 = 0.9f * a2 + 0.1f * __uint_as_float(xv.y << 16);
    float z3 = 0.9f * a3 + 0.1f * __uint_as_float(xv.y & 0xffff0000u);
    *(float4*)&zs[nloc][4 * ln] = make_float4(z0, z1, z2, z3);
    *(ushort4*)&zsb[nloc][4 * ln] = make_ushort4(f2b(z0), f2b(z1), f2b(z2), f2b(z3));
    __syncthreads();

    // ---- dense phase: mm = z @ W via MFMA. wave wv owns N-tile cols 16wv..16wv+15.
    // A-frag: lane reads zsb[row=ln][k=32s+8qt..], B-frag: WbT[col=16wv+ln][k..]
    floatx4 acc = (floatx4){0.f, 0.f, 0.f, 0.f};
#pragma unroll
    for (int s = 0; s < 2; ++s) {
        short8 af = *(const short8*)&zsb[ln][32 * s + 8 * qt];
        short8 bf = *(const short8*)&WbT[16 * wv + ln][32 * s + 8 * qt];
        acc = __builtin_amdgcn_mfma_f32_16x16x32_bf16(af, bf, acc, 0, 0, 0);
    }
    // C layout: col = lane&15 (j in tile), row = qt*4 + reg  -> row = node
    const float ob = 1.f - beta;
    const size_t base = (size_t)blockIdx.x * NPB;
#pragma unroll
    for (int r4 = 0; r4 < 4; ++r4) {
        const int node = qt * 4 + r4;
        const int j = 16 * wv + ln;
        float hv = fmaxf(ob * zs[node][j] + beta * acc[r4], 0.f);
        h_out[(base + node) * HID + j] = f2b(hv);
    }
}

// ---------------- final: log_softmax(h @ W1 + b1) ----------------
__global__ __launch_bounds__(256) void final_kernel(const unsigned short* __restrict__ h,
    const float* __restrict__ w1, const float* __restrict__ b1, float* __restrict__ out)
{
    const int m = threadIdx.x >> 6, j = threadIdx.x & 63;
    const long n = (long)blockIdx.x * 4 + m;
    const int jj = (j < NCLS) ? j : NCLS - 1;
    const ushort4* hrow = (const ushort4*)(h + n * HID);
    float acc = b1[jj];
#pragma unroll
    for (int k4 = 0; k4 < 16; ++k4) {
        ushort4 hv = hrow[k4];
        const int k = k4 * 4;
        acc = fmaf(b2f(hv.x), w1[(k + 0) * NCLS + jj], acc);
        acc = fmaf(b2f(hv.y), w1[(k + 1) * NCLS + jj], acc);
        acc = fmaf(b2f(hv.z), w1[(k + 2) * NCLS + jj], acc);
        acc = fmaf(b2f(hv.w), w1[(k + 3) * NCLS + jj], acc);
    }
    float lg = (j < NCLS) ? acc : -INFINITY;
    float mx = lg;
#pragma unroll
    for (int o = 32; o > 0; o >>= 1) mx = fmaxf(mx, __shfl_xor(mx, o, 64));
    float ex = (j < NCLS) ? expf(acc - mx) : 0.f;
    float sm = ex;
#pragma unroll
    for (int o = 32; o > 0; o >>= 1) sm += __shfl_xor(sm, o, 64);
    if (j < NCLS) out[n * NCLS + j] = acc - mx - logf(sm);
}

extern "C" void kernel_launch(void* const* d_in, const int* in_sizes, int n_in,
                              void* d_out, int out_size, void* d_ws, size_t ws_size,
                              hipStream_t stream)
{
    const float* x    = (const float*)d_in[0];
    const int*   esrc = (const int*)d_in[1];
    const int*   edst = (const int*)d_in[2];
    const float* ew   = (const float*)d_in[3];
    const float* l0w  = (const float*)d_in[4];
    const float* l0b  = (const float*)d_in[5];
    const float* cw   = (const float*)d_in[6];
    const float* l1w  = (const float*)d_in[7];
    const float* l1b  = (const float*)d_in[8];
    float* out = (float*)d_out;

    char* p = (char*)d_ws;
    unsigned short* h0 = (unsigned short*)p; p += (size_t)NNODES * HID * 2;
    unsigned short* hA = (unsigned short*)p; p += (size_t)NNODES * HID * 2;
    unsigned short* hB = (unsigned short*)p; p += (size_t)NNODES * HID * 2;
    int2*  srcw = (int2*)p;  p += ((size_t)NEDGES + 4 * NNODES) * 8;  // padded CSR
    int* offs   = (int*)p;   p += (size_t)(NNODES + 1) * 4;
    int* cursor = (int*)p;   p += (size_t)NNODES * 4;
    int* deg    = (int*)p;   p += (size_t)NNODES * 4;
    int* csum   = (int*)p;   p += 512;
    int* cbase  = (int*)p;   p += 512;

    const int nchunks = (NNODES + 1023) / 1024;   // 98

    hipMemsetAsync(deg, 0, NNODES * sizeof(int), stream);
    lin0_kernel<<<(NNODES + 127) / 128, 256, 0, stream>>>(x, l0w, l0b, h0);
    count_kernel<<<(NEDGES / 256) * 8, 256, 0, stream>>>(edst, deg);
    chunk_sum_kernel<<<nchunks, 1024, 0, stream>>>(deg, csum);
    chunk_base_kernel<<<1, 128, 0, stream>>>(csum, cbase, offs, nchunks);
    scan_kernel<<<nchunks, 1024, 0, stream>>>(deg, cbase, offs, cursor);
    scatter_kernel<<<(NEDGES / 256) * 8, 256, 0, stream>>>(esrc, edst, ew, cursor, srcw);
    pad_kernel<<<(NNODES + 255) / 256, 256, 0, stream>>>(offs, deg, srcw);

    const unsigned short* hin = h0;
    unsigned short* bufs[2] = { hA, hB };
    for (int l = 0; l < NLAYERS; ++l) {
        float beta = (float)log(0.5 / (double)(l + 1) + 1.0);
        unsigned short* hout = bufs[l & 1];
        spmm_layer_kernel<<<NNODES / NPB, 256, 0, stream>>>(
            hin, h0, hout, offs, srcw, cw + (size_t)l * HID * HID, beta);
        hin = hout;
    }
    final_kernel<<<NNODES / 4, 256, 0, stream>>>(hin, l1w, l1b, out);
}